// Round 4
// baseline (175.928 us; speedup 1.0000x reference)
//
#include <hip/hip_runtime.h>
#include <hip/hip_bf16.h>
#include <math.h>

// Dims fixed: S=512, H=4, W=4, D=512, dff=2048, NH=8, depth=64. M = 8192 rows.
//
// Key identity: q (8192x512) is consumed ONLY via per-group row-slice sums and
// a-weighted row combinations -> both are linear in q, so fold Wq/pe instead of
// materializing q:
//   rs[row,i]  = x[row,:] . wqslice[i,:] + peslice[row>>4, i]
//   a[g,:]     = softmax_j(rs[hw*512+j, i]),  g = hw*8+i
//   ctx[g,d]   = xa[g,:] . Wq[i*64+d,:] + sum_s'' ps[g,s'']*pe[hw*32+s'', i*64+d]
//     where xa[g,k] = sum_j a[g,j]*x[hw*512+j,k],  ps = 16-row bucket sums of a
// Then (unchanged, verified rounds 2-3):
//   adist[g,n] = ctx[g,:] . wsum[n,:]  (wsum = slice-folded Wfc)
//   o1 = LN(x + adist[g(row)]);  FFN via 256^2 pipelined bf16 MFMA + split-K;
//   out = LN(o1 + ffn)

typedef short short8 __attribute__((ext_vector_type(8)));
typedef float f32x4 __attribute__((ext_vector_type(4)));

#define LN10K_OVER_256 0.03597789207803197f

__device__ __forceinline__ void gload16(const short* g, short* l) {
  __builtin_amdgcn_global_load_lds(
      (const __attribute__((address_space(1))) void*)g,
      (__attribute__((address_space(3))) void*)l, 16, 0, 0);
}

#define BAR() do { asm volatile("" ::: "memory"); \
                   __builtin_amdgcn_s_barrier();  \
                   asm volatile("" ::: "memory"); } while (0)

__device__ __forceinline__ short8 ldsfrag(const short* opbuf, int R, int fq) {
  int sr = R >> 1;
  int sp = (((R & 1) << 2) | fq) ^ (sr & 7);
  return *(const short8*)(opbuf + sr * 64 + sp * 8);
}

// ============ 256x256/BK32, 8-wave, 3-deep pipelined bf16 GEMM ============
template<bool DOSTAGE, int WAITK>
__device__ __forceinline__ void tile_step(
    short* ldsb, int cur, int nx, int tt, int koff,
    const short* Ag0, const short* Ag1, const short* Bg0, const short* Bg1,
    int w, int fr, int fq, int wm, int wn, f32x4 (&acc)[8][4]) {
  const short* Abuf = ldsb + cur * 16384;
  const short* Bbuf = Abuf + 8192;
  short8 af[4], bfr[4];
#pragma unroll
  for (int m = 0; m < 4; ++m) af[m] = ldsfrag(Abuf, wm + m * 16 + fr, fq);
#pragma unroll
  for (int n = 0; n < 4; ++n) bfr[n] = ldsfrag(Bbuf, wn + n * 16 + fr, fq);
  if (DOSTAGE) {
    int kb = koff + (tt + 2) * 32;
    gload16(Ag0 + kb, ldsb + nx * 16384 + w * 512);
    gload16(Ag1 + kb, ldsb + nx * 16384 + 4096 + w * 512);
  }
  BAR();
  __builtin_amdgcn_s_setprio(1);
#pragma unroll
  for (int m = 0; m < 4; ++m)
#pragma unroll
    for (int n = 0; n < 4; ++n)
      acc[m][n] = __builtin_amdgcn_mfma_f32_16x16x32_bf16(af[m], bfr[n],
                                                          acc[m][n], 0, 0, 0);
  __builtin_amdgcn_s_setprio(0);
  BAR();
#pragma unroll
  for (int m = 0; m < 4; ++m) af[m] = ldsfrag(Abuf, wm + 64 + m * 16 + fr, fq);
  if (DOSTAGE) {
    int kb = koff + (tt + 2) * 32;
    gload16(Bg0 + kb, ldsb + nx * 16384 + 8192 + w * 512);
    gload16(Bg1 + kb, ldsb + nx * 16384 + 8192 + 4096 + w * 512);
  }
  BAR();
  __builtin_amdgcn_s_setprio(1);
#pragma unroll
  for (int m = 0; m < 4; ++m)
#pragma unroll
    for (int n = 0; n < 4; ++n)
      acc[4 + m][n] = __builtin_amdgcn_mfma_f32_16x16x32_bf16(af[m], bfr[n],
                                                              acc[4 + m][n], 0, 0, 0);
  __builtin_amdgcn_s_setprio(0);
  if (WAITK == 4) asm volatile("s_waitcnt vmcnt(4)" ::: "memory");
  else if (WAITK == 0) asm volatile("s_waitcnt vmcnt(0)" ::: "memory");
  BAR();
}

template<int MODE, int NT>
__global__ __launch_bounds__(512) void gemm256(
    const short* __restrict__ A, const short* __restrict__ B,
    const float* __restrict__ bias,
    short* __restrict__ C0, short* __restrict__ C1,
    short* __restrict__ C2, short* __restrict__ C3,
    int ldC, int ldA, int ldB) {
  __shared__ short lds[3 * 2 * 8192];  // 96 KiB
  const int t = threadIdx.x;
  const int w = t >> 6, l = t & 63;
  const int fr = l & 15, fq = l >> 4;
  const int wm = (w >> 2) * 128;
  const int wn = (w & 3) * 64;
  const int m0 = blockIdx.y * 256, n0 = blockIdx.x * 256;
  const int z = blockIdx.z;
  const int koff = z * (NT * 32);

  const int scont = (t & 7) ^ ((t >> 3) & 7);
  const int Rbase = ((t >> 3) << 1) | (scont >> 2);
  const int cg = (scont & 3) << 3;
  const short* Ag0 = A + (size_t)(m0 + Rbase) * ldA + cg;
  const short* Ag1 = Ag0 + (size_t)128 * ldA;
  const short* Bg0 = B + (size_t)(n0 + Rbase) * ldB + cg;
  const short* Bg1 = Bg0 + (size_t)128 * ldB;
  short* ldsb = &lds[0];

  gload16(Ag0 + koff, ldsb + w * 512);
  gload16(Ag1 + koff, ldsb + 4096 + w * 512);
  gload16(Bg0 + koff, ldsb + 8192 + w * 512);
  gload16(Bg1 + koff, ldsb + 8192 + 4096 + w * 512);
  gload16(Ag0 + koff + 32, ldsb + 16384 + w * 512);
  gload16(Ag1 + koff + 32, ldsb + 16384 + 4096 + w * 512);
  gload16(Bg0 + koff + 32, ldsb + 16384 + 8192 + w * 512);
  gload16(Bg1 + koff + 32, ldsb + 16384 + 8192 + 4096 + w * 512);
  asm volatile("s_waitcnt vmcnt(4)" ::: "memory");
  BAR();

  f32x4 acc[8][4] = {};
  int cur = 0;
#pragma unroll 1
  for (int tt = 0; tt < NT - 2; ++tt) {
    int nx = cur + 2; if (nx >= 3) nx -= 3;
    tile_step<true, 4>(ldsb, cur, nx, tt, koff, Ag0, Ag1, Bg0, Bg1,
                       w, fr, fq, wm, wn, acc);
    if (++cur == 3) cur = 0;
  }
  tile_step<false, 0>(ldsb, cur, 0, NT - 2, koff, Ag0, Ag1, Bg0, Bg1,
                      w, fr, fq, wm, wn, acc);
  { int c2 = cur + 1; if (c2 >= 3) c2 -= 3;
    tile_step<false, -1>(ldsb, c2, 0, NT - 1, koff, Ag0, Ag1, Bg0, Bg1,
                         w, fr, fq, wm, wn, acc); }

  short* myC;
  if (MODE == 1) myC = C0;
  else myC = (z == 0) ? C0 : (z == 1) ? C1 : (z == 2) ? C2 : C3;
  float bv[4];
  if (MODE == 1) {
#pragma unroll
    for (int n = 0; n < 4; ++n) bv[n] = bias[n0 + wn + n * 16 + fr];
  }
#pragma unroll
  for (int mm = 0; mm < 8; ++mm) {
#pragma unroll
    for (int n = 0; n < 4; ++n) {
      int col = n0 + wn + n * 16 + fr;
#pragma unroll
      for (int j = 0; j < 4; ++j) {
        int row = m0 + wm + mm * 16 + fq * 4 + j;
        float v = acc[mm][n][j];
        if (MODE == 1) v = fmaxf(v + bv[n], 0.f);
        __hip_bfloat16 hb = __float2bfloat16(v);
        myC[(size_t)row * ldC + col] = *(short*)&hb;
      }
    }
  }
}

// ============ folding / attention kernels (all fp32) ============

__global__ __launch_bounds__(256) void cvt_bf16(const float* __restrict__ in,
                                                short* __restrict__ out, int n8) {
  int i = blockIdx.x * 256 + threadIdx.x;
  if (i >= n8) return;
  const float4* p = (const float4*)(in + (size_t)i * 8);
  float4 a = p[0], b = p[1];
  union { __hip_bfloat16 h[8]; short8 s; } u;
  u.h[0] = __float2bfloat16(a.x); u.h[1] = __float2bfloat16(a.y);
  u.h[2] = __float2bfloat16(a.z); u.h[3] = __float2bfloat16(a.w);
  u.h[4] = __float2bfloat16(b.x); u.h[5] = __float2bfloat16(b.y);
  u.h[6] = __float2bfloat16(b.z); u.h[7] = __float2bfloat16(b.w);
  *(short8*)(out + (size_t)i * 8) = u.s;
}

// wqslice[i][k] = sum_{c in slice i} Wq[c][k]   (8 x 512)
__global__ __launch_bounds__(256) void wq_fold(const float* __restrict__ Wq,
                                               float* __restrict__ wqslice) {
  int idx = blockIdx.x * 256 + threadIdx.x;  // 4096
  int i = idx >> 9, k = idx & 511;
  float s = 0.f;
  for (int c = 0; c < 64; ++c) s += Wq[(size_t)(i * 64 + c) * 512 + k];
  wqslice[idx] = s;
}

// peslice[s][i] = sum_{kk in [i*32,(i+1)*32)} (sin(s*div_kk) + cos(s*div_kk))
__global__ __launch_bounds__(256) void pe_fold(float* __restrict__ peslice) {
  int idx = blockIdx.x * 256 + threadIdx.x;  // 4096
  int s = idx >> 3, i = idx & 7;
  float acc = 0.f;
  for (int kk = i * 32; kk < i * 32 + 32; ++kk) {
    float f = expf(-(float)kk * LN10K_OVER_256);
    float ang = (float)s * f;
    acc += sinf(ang) + cosf(ang);
  }
  peslice[idx] = acc;
}

// wsum[n,d] = sum_j Wfc[n, j*64+d]
__global__ __launch_bounds__(256) void wfc_fold(const float* __restrict__ Wfc,
                                                float* __restrict__ wsum) {
  int idx = blockIdx.x * 256 + threadIdx.x;
  int n = idx >> 6, d = idx & 63;
  float s = 0.f;
#pragma unroll
  for (int j = 0; j < 8; ++j) s += Wfc[(size_t)n * 512 + j * 64 + d];
  wsum[idx] = s;
}

// rs[row][i] = x[row,:] . wqslice[i,:] + peslice[row>>4][i]; 64 rows/block
__global__ __launch_bounds__(256) void attn_rs(const float* __restrict__ x,
                                               const float* __restrict__ wqslice,
                                               const float* __restrict__ peslice,
                                               float* __restrict__ rs) {
  int t = threadIdx.x;
  int row = blockIdx.x * 64 + (t >> 2);
  int sl2 = (t & 3) * 2;
  const float4* xr = (const float4*)(x + (size_t)row * 512);
  const float4* w0r = (const float4*)(wqslice + sl2 * 512);
  const float4* w1r = (const float4*)(wqslice + (sl2 + 1) * 512);
  float acc0 = 0.f, acc1 = 0.f;
#pragma unroll 4
  for (int kb = 0; kb < 128; ++kb) {
    float4 xv = xr[kb];
    float4 w0 = w0r[kb];
    float4 w1 = w1r[kb];
    acc0 += xv.x * w0.x + xv.y * w0.y + xv.z * w0.z + xv.w * w0.w;
    acc1 += xv.x * w1.x + xv.y * w1.y + xv.z * w1.z + xv.w * w1.w;
  }
  int s = row >> 4;
  rs[(size_t)row * 8 + sl2]     = acc0 + peslice[s * 8 + sl2];
  rs[(size_t)row * 8 + sl2 + 1] = acc1 + peslice[s * 8 + sl2 + 1];
}

// per g: a = softmax_j(rs), ps[s''] = 16-bucket sums of a
__global__ __launch_bounds__(256) void attn_softmax(const float* __restrict__ rs,
                                                    float* __restrict__ a,
                                                    float* __restrict__ ps) {
  int g = blockIdx.x;
  int hw = g >> 3, i = g & 7;
  int t = threadIdx.x;
  __shared__ float v[512];
  __shared__ float redA[4], redB[4], redm[1], reds[1];
  float r0 = rs[(size_t)(hw * 512 + t) * 8 + i];
  float r1 = rs[(size_t)(hw * 512 + t + 256) * 8 + i];
  float m = fmaxf(r0, r1);
  for (int off = 32; off; off >>= 1) m = fmaxf(m, __shfl_down(m, off));
  int wid = t >> 6, lane = t & 63;
  if (lane == 0) redA[wid] = m;
  __syncthreads();
  if (t == 0) redm[0] = fmaxf(fmaxf(redA[0], redA[1]), fmaxf(redA[2], redA[3]));
  __syncthreads();
  float M = redm[0];
  float e0 = expf(r0 - M), e1 = expf(r1 - M);
  float s = e0 + e1;
  for (int off = 32; off; off >>= 1) s += __shfl_down(s, off);
  if (lane == 0) redB[wid] = s;
  __syncthreads();
  if (t == 0) reds[0] = redB[0] + redB[1] + redB[2] + redB[3];
  __syncthreads();
  float inv = 1.f / reds[0];
  e0 *= inv; e1 *= inv;
  v[t] = e0; v[t + 256] = e1;
  a[(size_t)g * 512 + t] = e0;
  a[(size_t)g * 512 + t + 256] = e1;
  __syncthreads();
  if (t < 32) {
    float sps = 0.f;
#pragma unroll
    for (int u = 0; u < 16; ++u) sps += v[t * 16 + u];
    ps[g * 32 + t] = sps;
  }
}

// xa[g][k] = sum_j a[g][j] * x[hw*512+j][k]; grid (kc=4, hw=16)
__global__ __launch_bounds__(256) void attn_xa(const float* __restrict__ x,
                                               const float* __restrict__ a,
                                               float* __restrict__ xa) {
  int kc = blockIdx.x, hw = blockIdx.y;
  __shared__ float aS[8 * 512];
  int t = threadIdx.x;
  {
    const float4* asrc = (const float4*)(a + (size_t)hw * 8 * 512);
    float4* adst = (float4*)aS;
    for (int u = t; u < 1024; u += 256) adst[u] = asrc[u];
  }
  __syncthreads();
  int kk4 = t & 31, i = t >> 5;
  int col4 = kc * 32 + kk4;
  const float4* x4 = (const float4*)x;
  float ax = 0.f, ay = 0.f, az = 0.f, aw = 0.f;
  for (int jb = 0; jb < 64; ++jb) {
    float4 a0 = *(const float4*)&aS[i * 512 + jb * 8];
    float4 a1 = *(const float4*)&aS[i * 512 + jb * 8 + 4];
    float av[8] = {a0.x, a0.y, a0.z, a0.w, a1.x, a1.y, a1.z, a1.w};
#pragma unroll
    for (int u = 0; u < 8; ++u) {
      float4 xv = x4[(size_t)(hw * 512 + jb * 8 + u) * 128 + col4];
      ax += av[u] * xv.x; ay += av[u] * xv.y;
      az += av[u] * xv.z; aw += av[u] * xv.w;
    }
  }
  float4 o; o.x = ax; o.y = ay; o.z = az; o.w = aw;
  *(float4*)&xa[(size_t)(hw * 8 + i) * 512 + col4 * 4] = o;
}

// ctx[g][d] = xa[g,:].Wq[i*64+d,:] + sum_s'' ps[g,s'']*pe(hw*32+s'', i*64+d)
__global__ __launch_bounds__(256) void attn_ctx(const float* __restrict__ xa,
                                                const float* __restrict__ Wq,
                                                const float* __restrict__ ps,
                                                float* __restrict__ ctx) {
  int g = blockIdx.x;
  int hw = g >> 3, i = g & 7;
  int t = threadIdx.x;
  int d = t & 63, q4 = t >> 6;
  __shared__ float xaS[512];
  __shared__ float part[4][64];
  if (t < 128) ((float4*)xaS)[t] = ((const float4*)(xa + (size_t)g * 512))[t];
  __syncthreads();
  const float4* wrow = (const float4*)(Wq + (size_t)(i * 64 + d) * 512);
  float acc = 0.f;
#pragma unroll 8
  for (int kb = 0; kb < 32; ++kb) {
    float4 wv = wrow[q4 * 32 + kb];
    float4 xv = ((const float4*)xaS)[q4 * 32 + kb];
    acc += xv.x * wv.x + xv.y * wv.y + xv.z * wv.z + xv.w * wv.w;
  }
  part[q4][d] = acc;
  __syncthreads();
  if (t < 64) {
    float s = part[0][t] + part[1][t] + part[2][t] + part[3][t];
    int c = i * 64 + t;
    int kk = c >> 1;
    float f = expf(-(float)kk * LN10K_OVER_256);
    float pea = 0.f;
#pragma unroll 8
    for (int sp = 0; sp < 32; ++sp) {
      float ang = (float)(hw * 32 + sp) * f;
      float pv = (c & 1) ? cosf(ang) : sinf(ang);
      pea += ps[g * 32 + sp] * pv;
    }
    ctx[(size_t)g * 64 + t] = s + pea;
  }
}

// adist[g,n] = ctx[g,:].wsum[n,:]
__global__ __launch_bounds__(256) void attn_proj2(const float* __restrict__ ctx,
                                                  const float* __restrict__ wsum,
                                                  float* __restrict__ adist) {
  int g = blockIdx.x;
  __shared__ float c[64];
  int t = threadIdx.x;
  if (t < 64) c[t] = ctx[(size_t)g * 64 + t];
  __syncthreads();
  for (int n = t; n < 512; n += 256) {
    const float* wr = wsum + (size_t)n * 64;
    float s = 0.f;
#pragma unroll
    for (int d = 0; d < 64; ++d) s += c[d] * wr[d];
    adist[(size_t)g * 512 + n] = s;
  }
}

__global__ __launch_bounds__(256) void ln_kernel(
    const float* __restrict__ X, const float* __restrict__ Yadd,
    const float* __restrict__ gamma, const float* __restrict__ beta,
    float* __restrict__ Out, short* __restrict__ OutB, int groupedAdd) {
  int r = blockIdx.x;
  int t = threadIdx.x;
  const float* xr = X + (size_t)r * 512;
  const float* yr;
  if (groupedAdd) {
    int g = ((r >> 9) << 3) + ((r & 511) >> 6);
    yr = Yadd + (size_t)g * 512;
  } else {
    yr = Yadd + (size_t)r * 512;
  }
  float v0 = xr[t] + yr[t];
  float v1 = xr[t + 256] + yr[t + 256];
  float s = v0 + v1, sq = v0 * v0 + v1 * v1;
  __shared__ float red[6];
  __shared__ float redA[4];
  __shared__ float redB[4];
  for (int off = 32; off; off >>= 1) {
    s += __shfl_down(s, off);
    sq += __shfl_down(sq, off);
  }
  int wid = t >> 6, lane = t & 63;
  if (lane == 0) { redA[wid] = s; redB[wid] = sq; }
  __syncthreads();
  if (t == 0) {
    float S = redA[0] + redA[1] + redA[2] + redA[3];
    float Q = redB[0] + redB[1] + redB[2] + redB[3];
    float mean = S * (1.f / 512.f);
    float var = Q * (1.f / 512.f) - mean * mean;
    red[4] = mean;
    red[5] = rsqrtf(var + 1e-5f);
  }
  __syncthreads();
  float mean = red[4], inv = red[5];
  float r0 = (v0 - mean) * inv * gamma[t] + beta[t];
  float r1 = (v1 - mean) * inv * gamma[t + 256] + beta[t + 256];
  Out[(size_t)r * 512 + t] = r0;
  Out[(size_t)r * 512 + t + 256] = r1;
  if (OutB) {
    __hip_bfloat16 h0 = __float2bfloat16(r0);
    __hip_bfloat16 h1 = __float2bfloat16(r1);
    OutB[(size_t)r * 512 + t] = *(short*)&h0;
    OutB[(size_t)r * 512 + t + 256] = *(short*)&h1;
  }
}

__global__ __launch_bounds__(256) void ln2_fused(
    const float* __restrict__ o1,
    const short* __restrict__ p0, const short* __restrict__ p1,
    const short* __restrict__ p2, const short* __restrict__ p3,
    const float* __restrict__ b2, const float* __restrict__ gamma,
    const float* __restrict__ beta, float* __restrict__ Out) {
  int r = blockIdx.x;
  int t = threadIdx.x;
  size_t base = (size_t)r * 512;
  float v[2];
#pragma unroll
  for (int h = 0; h < 2; ++h) {
    int c = t + h * 256;
    float f = b2[c];
    f += __bfloat162float(*(const __hip_bfloat16*)&p0[base + c]);
    f += __bfloat162float(*(const __hip_bfloat16*)&p1[base + c]);
    f += __bfloat162float(*(const __hip_bfloat16*)&p2[base + c]);
    f += __bfloat162float(*(const __hip_bfloat16*)&p3[base + c]);
    v[h] = o1[base + c] + f;
  }
  float s = v[0] + v[1], sq = v[0] * v[0] + v[1] * v[1];
  __shared__ float red[6];
  __shared__ float redA[4];
  __shared__ float redB[4];
  for (int off = 32; off; off >>= 1) {
    s += __shfl_down(s, off);
    sq += __shfl_down(sq, off);
  }
  int wid = t >> 6, lane = t & 63;
  if (lane == 0) { redA[wid] = s; redB[wid] = sq; }
  __syncthreads();
  if (t == 0) {
    float S = redA[0] + redA[1] + redA[2] + redA[3];
    float Q = redB[0] + redB[1] + redB[2] + redB[3];
    float mean = S * (1.f / 512.f);
    float var = Q * (1.f / 512.f) - mean * mean;
    red[4] = mean;
    red[5] = rsqrtf(var + 1e-5f);
  }
  __syncthreads();
  float mean = red[4], inv = red[5];
  Out[base + t] = (v[0] - mean) * inv * gamma[t] + beta[t];
  Out[base + t + 256] = (v[1] - mean) * inv * gamma[t + 256] + beta[t + 256];
}

extern "C" void kernel_launch(void* const* d_in, const int* in_sizes, int n_in,
                              void* d_out, int out_size, void* d_ws, size_t ws_size,
                              hipStream_t stream) {
  const float* x   = (const float*)d_in[0];
  const float* Wq  = (const float*)d_in[1];
  const float* Wfc = (const float*)d_in[2];
  const float* W1  = (const float*)d_in[3];
  const float* b1  = (const float*)d_in[4];
  const float* W2  = (const float*)d_in[5];
  const float* b2  = (const float*)d_in[6];
  const float* g1  = (const float*)d_in[7];
  const float* be1 = (const float*)d_in[8];
  const float* g2  = (const float*)d_in[9];
  const float* be2 = (const float*)d_in[10];
  float* out = (float*)d_out;

  char* ws = (char*)d_ws;
  float* o1    = (float*)(ws);                       // 16 MB
  short* h1b   = (short*)(ws + (16u << 20));         // 32 MB
  short* pz0   = (short*)(ws + (48u << 20));         // 8 MB
  short* pz1   = (short*)(ws + (56u << 20));         // 8 MB
  short* o1b   = (short*)(ws + (64u << 20));         // 8 MB (dead after FFN1)
  short* pz2   = (short*)(ws + (64u << 20));         //   overlays o1b
  short* pz3   = (short*)(ws + (72u << 20));         // 8 MB
  short* W1b   = (short*)(ws + (80u << 20));         // 2 MB
  short* W2b   = (short*)(ws + (82u << 20));         // 2 MB
  char*  sm    = ws + (84u << 20);                   // small area (~1.2 MB)
  float* wqslice = (float*)(sm);                     // 16 KB
  float* peslice = (float*)(sm + (16u << 10));       // 16 KB
  float* ps      = (float*)(sm + (32u << 10));       // 16 KB
  float* ctx     = (float*)(sm + (48u << 10));       // 32 KB
  float* wsum    = (float*)(sm + (80u << 10));       // 128 KB
  float* adist   = (float*)(sm + (208u << 10));      // 256 KB
  float* rs      = (float*)(sm + (464u << 10));      // 256 KB
  float* a       = (float*)(sm + (720u << 10));      // 256 KB
  float* xa      = (float*)(sm + (976u << 10));      // 256 KB -> end ~85.2 MB

  // 0. weight conversions + folds
  cvt_bf16<<<512, 256, 0, stream>>>(W1, W1b, 131072);
  cvt_bf16<<<512, 256, 0, stream>>>(W2, W2b, 131072);
  wq_fold<<<16, 256, 0, stream>>>(Wq, wqslice);
  pe_fold<<<16, 256, 0, stream>>>(peslice);
  wfc_fold<<<128, 256, 0, stream>>>(Wfc, wsum);
  // 1. attention path (no q materialization)
  attn_rs<<<128, 256, 0, stream>>>(x, wqslice, peslice, rs);
  attn_softmax<<<128, 256, 0, stream>>>(rs, a, ps);
  attn_xa<<<dim3(4, 16), 256, 0, stream>>>(x, a, xa);
  attn_ctx<<<128, 256, 0, stream>>>(xa, Wq, ps, ctx);
  attn_proj2<<<128, 256, 0, stream>>>(ctx, wsum, adist);
  // 2. o1 = LN(x + attn) -> fp32 + bf16
  ln_kernel<<<8192, 256, 0, stream>>>(x, adist, g1, be1, o1, o1b, 1);
  // 3. h1b = relu(o1b @ W1b^T + b1)
  gemm256<1, 16><<<dim3(8, 32, 1), 512, 0, stream>>>(
      o1b, W1b, b1, h1b, h1b, h1b, h1b, 2048, 512, 512);
  // 4. FFN2 split-K=4 partials (bf16)
  gemm256<3, 16><<<dim3(2, 32, 4), 512, 0, stream>>>(
      h1b, W2b, nullptr, pz0, pz1, pz2, pz3, 512, 2048, 2048);
  // 5. d_out = LN(o1 + sum partials + b2)
  ln2_fused<<<8192, 256, 0, stream>>>(o1, pz0, pz1, pz2, pz3, b2, g2, be2, out);
}

// Round 5
// 141.252 us; speedup vs baseline: 1.2455x; 1.2455x over previous
//
#include <hip/hip_runtime.h>
#include <hip/hip_bf16.h>
#include <math.h>

// Dims fixed: S=512, H=4, W=4, D=512, dff=2048, NH=8, depth=64. M = 8192 rows.
//
// Pipeline (6 launches):
//  1. prep: xb,W1b,W2b,Wqb bf16 converts + wsum[n,d]=sum_j Wfc[n,j*64+d]
//  2. qb = xb @ Wqb^T + PE (bf16, gemm256 3-deep pipelined, MODE 0)
//  3. attn_g (128 blocks = one per group g=hw*8+i):
//       slice = qb[hw*512+j, i*64+d] -> LDS; rs[j]=sum_d slice;
//       a=softmax(rs); ctx[d]=sum_j a[j]*slice[j][d];
//       adist[n]=sum_d ctx[d]*wsum[n][d];
//       LN1 for rows R=hw*512+i*64+[0,64): o1=LN(x+adist), o1b=bf16(o1)
//  4. h1b = relu(o1b @ W1b^T + b1)   (gemm256 MODE 1)
//  5. FFN2 split-K=4 bf16 partials   (gemm256 MODE 3)
//  6. out = LN(o1 + sum partials + b2)  (ln2_fused)

typedef short short8 __attribute__((ext_vector_type(8)));
typedef float f32x4 __attribute__((ext_vector_type(4)));

#define LN10K_OVER_256 0.03597789207803197f

__device__ __forceinline__ void gload16(const short* g, short* l) {
  __builtin_amdgcn_global_load_lds(
      (const __attribute__((address_space(1))) void*)g,
      (__attribute__((address_space(3))) void*)l, 16, 0, 0);
}

#define BAR() do { asm volatile("" ::: "memory"); \
                   __builtin_amdgcn_s_barrier();  \
                   asm volatile("" ::: "memory"); } while (0)

__device__ __forceinline__ short8 ldsfrag(const short* opbuf, int R, int fq) {
  int sr = R >> 1;
  int sp = (((R & 1) << 2) | fq) ^ (sr & 7);
  return *(const short8*)(opbuf + sr * 64 + sp * 8);
}

// ============ 256x256/BK32, 8-wave, 3-deep pipelined bf16 GEMM ============
template<bool DOSTAGE, int WAITK>
__device__ __forceinline__ void tile_step(
    short* ldsb, int cur, int nx, int tt, int koff,
    const short* Ag0, const short* Ag1, const short* Bg0, const short* Bg1,
    int w, int fr, int fq, int wm, int wn, f32x4 (&acc)[8][4]) {
  const short* Abuf = ldsb + cur * 16384;
  const short* Bbuf = Abuf + 8192;
  short8 af[4], bfr[4];
#pragma unroll
  for (int m = 0; m < 4; ++m) af[m] = ldsfrag(Abuf, wm + m * 16 + fr, fq);
#pragma unroll
  for (int n = 0; n < 4; ++n) bfr[n] = ldsfrag(Bbuf, wn + n * 16 + fr, fq);
  if (DOSTAGE) {
    int kb = koff + (tt + 2) * 32;
    gload16(Ag0 + kb, ldsb + nx * 16384 + w * 512);
    gload16(Ag1 + kb, ldsb + nx * 16384 + 4096 + w * 512);
  }
  BAR();
  __builtin_amdgcn_s_setprio(1);
#pragma unroll
  for (int m = 0; m < 4; ++m)
#pragma unroll
    for (int n = 0; n < 4; ++n)
      acc[m][n] = __builtin_amdgcn_mfma_f32_16x16x32_bf16(af[m], bfr[n],
                                                          acc[m][n], 0, 0, 0);
  __builtin_amdgcn_s_setprio(0);
  BAR();
#pragma unroll
  for (int m = 0; m < 4; ++m) af[m] = ldsfrag(Abuf, wm + 64 + m * 16 + fr, fq);
  if (DOSTAGE) {
    int kb = koff + (tt + 2) * 32;
    gload16(Bg0 + kb, ldsb + nx * 16384 + 8192 + w * 512);
    gload16(Bg1 + kb, ldsb + nx * 16384 + 8192 + 4096 + w * 512);
  }
  BAR();
  __builtin_amdgcn_s_setprio(1);
#pragma unroll
  for (int m = 0; m < 4; ++m)
#pragma unroll
    for (int n = 0; n < 4; ++n)
      acc[4 + m][n] = __builtin_amdgcn_mfma_f32_16x16x32_bf16(af[m], bfr[n],
                                                              acc[4 + m][n], 0, 0, 0);
  __builtin_amdgcn_s_setprio(0);
  if (WAITK == 4) asm volatile("s_waitcnt vmcnt(4)" ::: "memory");
  else if (WAITK == 0) asm volatile("s_waitcnt vmcnt(0)" ::: "memory");
  BAR();
}

// MODE 0: +PE -> bf16 C0. MODE 1: relu(+bias) -> bf16 C0. MODE 3: raw -> bf16 C{z}.
template<int MODE, int NT>
__global__ __launch_bounds__(512) void gemm256(
    const short* __restrict__ A, const short* __restrict__ B,
    const float* __restrict__ bias,
    short* __restrict__ C0, short* __restrict__ C1,
    short* __restrict__ C2, short* __restrict__ C3,
    int ldC, int ldA, int ldB) {
  __shared__ short lds[3 * 2 * 8192];  // 96 KiB
  const int t = threadIdx.x;
  const int w = t >> 6, l = t & 63;
  const int fr = l & 15, fq = l >> 4;
  const int wm = (w >> 2) * 128;
  const int wn = (w & 3) * 64;
  const int m0 = blockIdx.y * 256, n0 = blockIdx.x * 256;
  const int z = blockIdx.z;
  const int koff = z * (NT * 32);

  const int scont = (t & 7) ^ ((t >> 3) & 7);
  const int Rbase = ((t >> 3) << 1) | (scont >> 2);
  const int cg = (scont & 3) << 3;
  const short* Ag0 = A + (size_t)(m0 + Rbase) * ldA + cg;
  const short* Ag1 = Ag0 + (size_t)128 * ldA;
  const short* Bg0 = B + (size_t)(n0 + Rbase) * ldB + cg;
  const short* Bg1 = Bg0 + (size_t)128 * ldB;
  short* ldsb = &lds[0];

  gload16(Ag0 + koff, ldsb + w * 512);
  gload16(Ag1 + koff, ldsb + 4096 + w * 512);
  gload16(Bg0 + koff, ldsb + 8192 + w * 512);
  gload16(Bg1 + koff, ldsb + 8192 + 4096 + w * 512);
  gload16(Ag0 + koff + 32, ldsb + 16384 + w * 512);
  gload16(Ag1 + koff + 32, ldsb + 16384 + 4096 + w * 512);
  gload16(Bg0 + koff + 32, ldsb + 16384 + 8192 + w * 512);
  gload16(Bg1 + koff + 32, ldsb + 16384 + 8192 + 4096 + w * 512);
  asm volatile("s_waitcnt vmcnt(4)" ::: "memory");
  BAR();

  f32x4 acc[8][4] = {};
  int cur = 0;
#pragma unroll 1
  for (int tt = 0; tt < NT - 2; ++tt) {
    int nx = cur + 2; if (nx >= 3) nx -= 3;
    tile_step<true, 4>(ldsb, cur, nx, tt, koff, Ag0, Ag1, Bg0, Bg1,
                       w, fr, fq, wm, wn, acc);
    if (++cur == 3) cur = 0;
  }
  tile_step<false, 0>(ldsb, cur, 0, NT - 2, koff, Ag0, Ag1, Bg0, Bg1,
                      w, fr, fq, wm, wn, acc);
  { int c2 = cur + 1; if (c2 >= 3) c2 -= 3;
    tile_step<false, -1>(ldsb, c2, 0, NT - 1, koff, Ag0, Ag1, Bg0, Bg1,
                         w, fr, fq, wm, wn, acc); }

  short* myC;
  if (MODE == 1 || MODE == 0) myC = C0;
  else myC = (z == 0) ? C0 : (z == 1) ? C1 : (z == 2) ? C2 : C3;
  float bv[4];
  float fc[4];
  int oddc[4];
  if (MODE == 1) {
#pragma unroll
    for (int n = 0; n < 4; ++n) bv[n] = bias[n0 + wn + n * 16 + fr];
  }
  if (MODE == 0) {
#pragma unroll
    for (int n = 0; n < 4; ++n) {
      int col = n0 + wn + n * 16 + fr;
      fc[n] = expf(-(float)(col >> 1) * LN10K_OVER_256);
      oddc[n] = col & 1;
    }
  }
#pragma unroll
  for (int mm = 0; mm < 8; ++mm) {
#pragma unroll
    for (int n = 0; n < 4; ++n) {
      int col = n0 + wn + n * 16 + fr;
#pragma unroll
      for (int j = 0; j < 4; ++j) {
        int row = m0 + wm + mm * 16 + fq * 4 + j;
        float v = acc[mm][n][j];
        if (MODE == 1) v = fmaxf(v + bv[n], 0.f);
        if (MODE == 0) {
          float ang = (float)(row >> 4) * fc[n];
          v += oddc[n] ? cosf(ang) : sinf(ang);
        }
        __hip_bfloat16 hb = __float2bfloat16(v);
        myC[(size_t)row * ldC + col] = *(short*)&hb;
      }
    }
  }
}

// ============ prep: all converts + wfc fold in ONE launch ============
__device__ __forceinline__ void cvt8(const float* in, short* out, int i) {
  const float4* p = (const float4*)(in + (size_t)i * 8);
  float4 a = p[0], b = p[1];
  union { __hip_bfloat16 h[8]; short8 s; } u;
  u.h[0] = __float2bfloat16(a.x); u.h[1] = __float2bfloat16(a.y);
  u.h[2] = __float2bfloat16(a.z); u.h[3] = __float2bfloat16(a.w);
  u.h[4] = __float2bfloat16(b.x); u.h[5] = __float2bfloat16(b.y);
  u.h[6] = __float2bfloat16(b.z); u.h[7] = __float2bfloat16(b.w);
  *(short8*)(out + (size_t)i * 8) = u.s;
}

__global__ __launch_bounds__(256) void prep(
    const float* __restrict__ x, const float* __restrict__ W1,
    const float* __restrict__ W2, const float* __restrict__ Wq,
    const float* __restrict__ Wfc,
    short* __restrict__ xb, short* __restrict__ W1b,
    short* __restrict__ W2b, short* __restrict__ Wqb,
    float* __restrict__ wsum) {
  int b = blockIdx.x, t = threadIdx.x;
  if (b < 2048) {
    cvt8(x, xb, b * 256 + t);
  } else if (b < 2560) {
    cvt8(W1, W1b, (b - 2048) * 256 + t);
  } else if (b < 3072) {
    cvt8(W2, W2b, (b - 2560) * 256 + t);
  } else if (b < 3200) {
    cvt8(Wq, Wqb, (b - 3072) * 256 + t);
  } else {
    int idx = (b - 3200) * 256 + t;  // 32768
    int n = idx >> 6, d = idx & 63;
    float s = 0.f;
#pragma unroll
    for (int j = 0; j < 8; ++j) s += Wfc[(size_t)n * 512 + j * 64 + d];
    wsum[idx] = s;
  }
}

// ============ attn_g: per-group attention + fused LN1 (128 blocks) ============
__global__ __launch_bounds__(256) void attn_g(
    const short* __restrict__ qb, const float* __restrict__ x,
    const float* __restrict__ wsum, const float* __restrict__ g1,
    const float* __restrict__ be1, float* __restrict__ o1,
    short* __restrict__ o1b) {
  int g = blockIdx.x;
  int hw = g >> 3, i = g & 7;
  int t = threadIdx.x;
  __shared__ short sl[512 * 72];       // [512 rows][64 cols + 8 pad] bf16
  __shared__ float a_[512];
  __shared__ float adist_[512];
  __shared__ float pctx[4][64];
  __shared__ float gb[1024];
  __shared__ float redA[4], redB[4], redMS[2];
  __shared__ float ctxs[64];

  // gamma/beta
  gb[t] = g1[t]; gb[t + 256] = g1[t + 256];
  gb[512 + t] = be1[t]; gb[768 + t] = be1[t + 256];

  // stage qb slice: rows hw*512+j, cols i*64..+64
  {
    const short* qsrc = qb + ((size_t)hw * 512) * 512 + i * 64;
    int chunk = t & 7, jr0 = t >> 3;
#pragma unroll
    for (int rep = 0; rep < 16; ++rep) {
      int j = jr0 + rep * 32;
      *(short8*)&sl[j * 72 + chunk * 8] =
          *(const short8*)(qsrc + (size_t)j * 512 + chunk * 8);
    }
  }
  __syncthreads();

  // rs for rows t and t+256
  float r0 = 0.f, r1 = 0.f;
#pragma unroll
  for (int c = 0; c < 8; ++c) {
    union { short8 s8; short e[8]; } u0, u1;
    u0.s8 = *(const short8*)&sl[t * 72 + c * 8];
    u1.s8 = *(const short8*)&sl[(t + 256) * 72 + c * 8];
#pragma unroll
    for (int u = 0; u < 8; ++u) {
      r0 += __bfloat162float(*(__hip_bfloat16*)&u0.e[u]);
      r1 += __bfloat162float(*(__hip_bfloat16*)&u1.e[u]);
    }
  }
  // block softmax over 512
  float m = fmaxf(r0, r1);
  for (int off = 32; off; off >>= 1) m = fmaxf(m, __shfl_down(m, off));
  int wid = t >> 6, lane = t & 63;
  if (lane == 0) redA[wid] = m;
  __syncthreads();
  if (t == 0) redMS[0] = fmaxf(fmaxf(redA[0], redA[1]), fmaxf(redA[2], redA[3]));
  __syncthreads();
  float M = redMS[0];
  float e0 = expf(r0 - M), e1 = expf(r1 - M);
  float s = e0 + e1;
  for (int off = 32; off; off >>= 1) s += __shfl_down(s, off);
  if (lane == 0) redB[wid] = s;
  __syncthreads();
  if (t == 0) redMS[1] = redB[0] + redB[1] + redB[2] + redB[3];
  __syncthreads();
  float inv = 1.f / redMS[1];
  a_[t] = e0 * inv;
  a_[t + 256] = e1 * inv;
  __syncthreads();

  // ctx[d] = sum_j a[j]*slice[j][d]
  {
    int d = t & 63, seg = t >> 6;
    float acc = 0.f;
    for (int mm = seg * 128; mm < seg * 128 + 128; ++mm)
      acc += a_[mm] * __bfloat162float(*(__hip_bfloat16*)&sl[mm * 72 + d]);
    pctx[seg][d] = acc;
  }
  __syncthreads();
  if (t < 64) ctxs[t] = pctx[0][t] + pctx[1][t] + pctx[2][t] + pctx[3][t];
  __syncthreads();

  // adist[n] = sum_d ctx[d]*wsum[n][d]
  for (int n = t; n < 512; n += 256) {
    const float4* wr = (const float4*)(wsum + (size_t)n * 64);
    float sa = 0.f;
#pragma unroll
    for (int db = 0; db < 16; ++db) {
      float4 wv = wr[db];
      float4 cv = *(const float4*)&ctxs[db * 4];
      sa += cv.x * wv.x + cv.y * wv.y + cv.z * wv.z + cv.w * wv.w;
    }
    adist_[n] = sa;
  }
  __syncthreads();

  // fused LN1 for this block's 64 rows: R = hw*512 + i*64 + [0,64)
  const float4* x4 = (const float4*)x;
  int w = t >> 6;  // lane from above
#pragma unroll 1
  for (int u = 0; u < 16; ++u) {
    int j = i * 64 + w * 16 + u;
    size_t R = (size_t)hw * 512 + j;
    float4 xv0 = x4[R * 128 + lane * 2];
    float4 xv1 = x4[R * 128 + lane * 2 + 1];
    float4 a0 = *(const float4*)&adist_[lane * 8];
    float4 a1 = *(const float4*)&adist_[lane * 8 + 4];
    float v[8] = {xv0.x + a0.x, xv0.y + a0.y, xv0.z + a0.z, xv0.w + a0.w,
                  xv1.x + a1.x, xv1.y + a1.y, xv1.z + a1.z, xv1.w + a1.w};
    float sm_ = 0.f, sq = 0.f;
#pragma unroll
    for (int q = 0; q < 8; ++q) { sm_ += v[q]; sq += v[q] * v[q]; }
    for (int off = 32; off; off >>= 1) {
      sm_ += __shfl_xor(sm_, off);
      sq += __shfl_xor(sq, off);
    }
    float mean = sm_ * (1.f / 512.f);
    float var = sq * (1.f / 512.f) - mean * mean;
    float rinv = rsqrtf(var + 1e-5f);
    float o[8];
    union { __hip_bfloat16 h[8]; short8 s8; } ub;
#pragma unroll
    for (int q = 0; q < 8; ++q) {
      int c = lane * 8 + q;
      o[q] = (v[q] - mean) * rinv * gb[c] + gb[512 + c];
      ub.h[q] = __float2bfloat16(o[q]);
    }
    float4 w0 = {o[0], o[1], o[2], o[3]};
    float4 w1 = {o[4], o[5], o[6], o[7]};
    *(float4*)&o1[R * 512 + lane * 8] = w0;
    *(float4*)&o1[R * 512 + lane * 8 + 4] = w1;
    *(short8*)&o1b[R * 512 + lane * 8] = ub.s8;
  }
}

// ============ final LN fused with split-K reduce ============
__global__ __launch_bounds__(256) void ln2_fused(
    const float* __restrict__ o1,
    const short* __restrict__ p0, const short* __restrict__ p1,
    const short* __restrict__ p2, const short* __restrict__ p3,
    const float* __restrict__ b2, const float* __restrict__ gamma,
    const float* __restrict__ beta, float* __restrict__ Out) {
  int r = blockIdx.x;
  int t = threadIdx.x;
  size_t base = (size_t)r * 512;
  float v[2];
#pragma unroll
  for (int h = 0; h < 2; ++h) {
    int c = t + h * 256;
    float f = b2[c];
    f += __bfloat162float(*(const __hip_bfloat16*)&p0[base + c]);
    f += __bfloat162float(*(const __hip_bfloat16*)&p1[base + c]);
    f += __bfloat162float(*(const __hip_bfloat16*)&p2[base + c]);
    f += __bfloat162float(*(const __hip_bfloat16*)&p3[base + c]);
    v[h] = o1[base + c] + f;
  }
  float s = v[0] + v[1], sq = v[0] * v[0] + v[1] * v[1];
  __shared__ float red[6];
  __shared__ float redA[4];
  __shared__ float redB[4];
  for (int off = 32; off; off >>= 1) {
    s += __shfl_down(s, off);
    sq += __shfl_down(sq, off);
  }
  int wid = t >> 6, lane = t & 63;
  if (lane == 0) { redA[wid] = s; redB[wid] = sq; }
  __syncthreads();
  if (t == 0) {
    float S = redA[0] + redA[1] + redA[2] + redA[3];
    float Q = redB[0] + redB[1] + redB[2] + redB[3];
    float mean = S * (1.f / 512.f);
    float var = Q * (1.f / 512.f) - mean * mean;
    red[4] = mean;
    red[5] = rsqrtf(var + 1e-5f);
  }
  __syncthreads();
  float mean = red[4], inv = red[5];
  Out[base + t] = (v[0] - mean) * inv * gamma[t] + beta[t];
  Out[base + t + 256] = (v[1] - mean) * inv * gamma[t + 256] + beta[t + 256];
}

extern "C" void kernel_launch(void* const* d_in, const int* in_sizes, int n_in,
                              void* d_out, int out_size, void* d_ws, size_t ws_size,
                              hipStream_t stream) {
  const float* x   = (const float*)d_in[0];
  const float* Wq  = (const float*)d_in[1];
  const float* Wfc = (const float*)d_in[2];
  const float* W1  = (const float*)d_in[3];
  const float* b1  = (const float*)d_in[4];
  const float* W2  = (const float*)d_in[5];
  const float* b2  = (const float*)d_in[6];
  const float* g1  = (const float*)d_in[7];
  const float* be1 = (const float*)d_in[8];
  const float* g2  = (const float*)d_in[9];
  const float* be2 = (const float*)d_in[10];
  float* out = (float*)d_out;

  char* ws = (char*)d_ws;
  float* o1   = (float*)(ws);                  // 16 MB
  short* h1b  = (short*)(ws + (16u << 20));    // 32 MB
  short* pz0  = (short*)(ws + (48u << 20));    // 8 MB
  short* pz1  = (short*)(ws + (56u << 20));    // 8 MB
  short* o1b  = (short*)(ws + (64u << 20));    // 8 MB (dead after FFN1)
  short* pz2  = (short*)(ws + (64u << 20));    //   overlays o1b
  short* pz3  = (short*)(ws + (72u << 20));    // 8 MB
  short* W1b  = (short*)(ws + (80u << 20));    // 2 MB
  short* W2b  = (short*)(ws + (82u << 20));    // 2 MB
  short* Wqb  = (short*)(ws + (84u << 20));    // 0.5 MB
  short* xb   = (short*)(ws + (85u << 20));    // 8 MB
  short* qb   = (short*)(ws + (93u << 20));    // 8 MB
  float* wsum = (float*)(ws + (101u << 20));   // 128 KB  (end ~101.2 MB)

  // 1. all converts + wfc fold
  prep<<<3328, 256, 0, stream>>>(x, W1, W2, Wq, Wfc, xb, W1b, W2b, Wqb, wsum);
  // 2. qb = xb @ Wqb^T + PE (bf16)
  gemm256<0, 16><<<dim3(2, 32, 1), 512, 0, stream>>>(
      xb, Wqb, nullptr, qb, qb, qb, qb, 512, 512, 512);
  // 3. per-group attention + fused LN1
  attn_g<<<128, 256, 0, stream>>>(qb, x, wsum, g1, be1, o1, o1b);
  // 4. h1b = relu(o1b @ W1b^T + b1)
  gemm256<1, 16><<<dim3(8, 32, 1), 512, 0, stream>>>(
      o1b, W1b, b1, h1b, h1b, h1b, h1b, 2048, 512, 512);
  // 5. FFN2 split-K=4 partials (bf16)
  gemm256<3, 16><<<dim3(2, 32, 4), 512, 0, stream>>>(
      h1b, W2b, nullptr, pz0, pz1, pz2, pz3, 512, 2048, 2048);
  // 6. out = LN(o1 + sum partials + b2)
  ln2_fused<<<8192, 256, 0, stream>>>(o1, pz0, pz1, pz2, pz3, b2, g2, be2, out);
}

// Round 6
// 115.648 us; speedup vs baseline: 1.5212x; 1.2214x over previous
//
#include <hip/hip_runtime.h>
#include <hip/hip_bf16.h>
#include <math.h>

// Dims fixed: S=512, H=4, W=4, D=512, dff=2048, NH=8, depth=64. M = 8192 rows.
//
// Pipeline (6 launches):
//  1. prep: xb,W1b,W2b,Wqb bf16 converts + wsum fold + PE TABLE (512x512 fp32,
//     one sin/cos per thread -- kills the Payne-Hanek serial chain that made
//     every previous MODE-0 epilogue ~100us)
//  2. qb = xb @ Wqb^T + pe[row>>4][col] (bf16, gemm256, MODE 0, pe via `bias` arg)
//  3. attn_g (128 blocks): group attention + fused LN1 -> o1 (f32) + o1b (bf16)
//  4. h1b = relu(o1b @ W1b^T + b1)   (gemm256 MODE 1)
//  5. FFN2 split-K=4 bf16 partials   (gemm256 MODE 3)
//  6. out = LN(o1 + sum partials + b2)  (ln2_fused)

typedef short short8 __attribute__((ext_vector_type(8)));
typedef float f32x4 __attribute__((ext_vector_type(4)));

#define LN10K_OVER_256 0.03597789207803197f

__device__ __forceinline__ void gload16(const short* g, short* l) {
  __builtin_amdgcn_global_load_lds(
      (const __attribute__((address_space(1))) void*)g,
      (__attribute__((address_space(3))) void*)l, 16, 0, 0);
}

#define BAR() do { asm volatile("" ::: "memory"); \
                   __builtin_amdgcn_s_barrier();  \
                   asm volatile("" ::: "memory"); } while (0)

__device__ __forceinline__ short8 ldsfrag(const short* opbuf, int R, int fq) {
  int sr = R >> 1;
  int sp = (((R & 1) << 2) | fq) ^ (sr & 7);
  return *(const short8*)(opbuf + sr * 64 + sp * 8);
}

// ============ 256x256/BK32, 8-wave, 3-deep pipelined bf16 GEMM ============
template<bool DOSTAGE, int WAITK>
__device__ __forceinline__ void tile_step(
    short* ldsb, int cur, int nx, int tt, int koff,
    const short* Ag0, const short* Ag1, const short* Bg0, const short* Bg1,
    int w, int fr, int fq, int wm, int wn, f32x4 (&acc)[8][4]) {
  const short* Abuf = ldsb + cur * 16384;
  const short* Bbuf = Abuf + 8192;
  short8 af[4], bfr[4];
#pragma unroll
  for (int m = 0; m < 4; ++m) af[m] = ldsfrag(Abuf, wm + m * 16 + fr, fq);
#pragma unroll
  for (int n = 0; n < 4; ++n) bfr[n] = ldsfrag(Bbuf, wn + n * 16 + fr, fq);
  if (DOSTAGE) {
    int kb = koff + (tt + 2) * 32;
    gload16(Ag0 + kb, ldsb + nx * 16384 + w * 512);
    gload16(Ag1 + kb, ldsb + nx * 16384 + 4096 + w * 512);
  }
  BAR();
  __builtin_amdgcn_s_setprio(1);
#pragma unroll
  for (int m = 0; m < 4; ++m)
#pragma unroll
    for (int n = 0; n < 4; ++n)
      acc[m][n] = __builtin_amdgcn_mfma_f32_16x16x32_bf16(af[m], bfr[n],
                                                          acc[m][n], 0, 0, 0);
  __builtin_amdgcn_s_setprio(0);
  BAR();
#pragma unroll
  for (int m = 0; m < 4; ++m) af[m] = ldsfrag(Abuf, wm + 64 + m * 16 + fr, fq);
  if (DOSTAGE) {
    int kb = koff + (tt + 2) * 32;
    gload16(Bg0 + kb, ldsb + nx * 16384 + 8192 + w * 512);
    gload16(Bg1 + kb, ldsb + nx * 16384 + 8192 + 4096 + w * 512);
  }
  BAR();
  __builtin_amdgcn_s_setprio(1);
#pragma unroll
  for (int m = 0; m < 4; ++m)
#pragma unroll
    for (int n = 0; n < 4; ++n)
      acc[4 + m][n] = __builtin_amdgcn_mfma_f32_16x16x32_bf16(af[m], bfr[n],
                                                              acc[4 + m][n], 0, 0, 0);
  __builtin_amdgcn_s_setprio(0);
  if (WAITK == 4) asm volatile("s_waitcnt vmcnt(4)" ::: "memory");
  else if (WAITK == 0) asm volatile("s_waitcnt vmcnt(0)" ::: "memory");
  BAR();
}

// MODE 0: +pe table (via `bias`) -> bf16 C0. MODE 1: relu(+bias) -> bf16 C0.
// MODE 3: raw -> bf16 C{z} (split-K partial).
template<int MODE, int NT>
__global__ __launch_bounds__(512) void gemm256(
    const short* __restrict__ A, const short* __restrict__ B,
    const float* __restrict__ bias,
    short* __restrict__ C0, short* __restrict__ C1,
    short* __restrict__ C2, short* __restrict__ C3,
    int ldC, int ldA, int ldB) {
  __shared__ short lds[3 * 2 * 8192];  // 96 KiB
  const int t = threadIdx.x;
  const int w = t >> 6, l = t & 63;
  const int fr = l & 15, fq = l >> 4;
  const int wm = (w >> 2) * 128;
  const int wn = (w & 3) * 64;
  const int m0 = blockIdx.y * 256, n0 = blockIdx.x * 256;
  const int z = blockIdx.z;
  const int koff = z * (NT * 32);

  const int scont = (t & 7) ^ ((t >> 3) & 7);
  const int Rbase = ((t >> 3) << 1) | (scont >> 2);
  const int cg = (scont & 3) << 3;
  const short* Ag0 = A + (size_t)(m0 + Rbase) * ldA + cg;
  const short* Ag1 = Ag0 + (size_t)128 * ldA;
  const short* Bg0 = B + (size_t)(n0 + Rbase) * ldB + cg;
  const short* Bg1 = Bg0 + (size_t)128 * ldB;
  short* ldsb = &lds[0];

  gload16(Ag0 + koff, ldsb + w * 512);
  gload16(Ag1 + koff, ldsb + 4096 + w * 512);
  gload16(Bg0 + koff, ldsb + 8192 + w * 512);
  gload16(Bg1 + koff, ldsb + 8192 + 4096 + w * 512);
  gload16(Ag0 + koff + 32, ldsb + 16384 + w * 512);
  gload16(Ag1 + koff + 32, ldsb + 16384 + 4096 + w * 512);
  gload16(Bg0 + koff + 32, ldsb + 16384 + 8192 + w * 512);
  gload16(Bg1 + koff + 32, ldsb + 16384 + 8192 + 4096 + w * 512);
  asm volatile("s_waitcnt vmcnt(4)" ::: "memory");
  BAR();

  f32x4 acc[8][4] = {};
  int cur = 0;
#pragma unroll 1
  for (int tt = 0; tt < NT - 2; ++tt) {
    int nx = cur + 2; if (nx >= 3) nx -= 3;
    tile_step<true, 4>(ldsb, cur, nx, tt, koff, Ag0, Ag1, Bg0, Bg1,
                       w, fr, fq, wm, wn, acc);
    if (++cur == 3) cur = 0;
  }
  tile_step<false, 0>(ldsb, cur, 0, NT - 2, koff, Ag0, Ag1, Bg0, Bg1,
                      w, fr, fq, wm, wn, acc);
  { int c2 = cur + 1; if (c2 >= 3) c2 -= 3;
    tile_step<false, -1>(ldsb, c2, 0, NT - 1, koff, Ag0, Ag1, Bg0, Bg1,
                         w, fr, fq, wm, wn, acc); }

  short* myC;
  if (MODE == 1 || MODE == 0) myC = C0;
  else myC = (z == 0) ? C0 : (z == 1) ? C1 : (z == 2) ? C2 : C3;
  float bv[4];
  if (MODE == 1) {
#pragma unroll
    for (int n = 0; n < 4; ++n) bv[n] = bias[n0 + wn + n * 16 + fr];
  }
#pragma unroll
  for (int mm = 0; mm < 8; ++mm) {
    const float* per = nullptr;
    if (MODE == 0) {
      int s = (m0 + wm + mm * 16) >> 4;  // uniform over fq*4+j within this mm
      per = bias + (size_t)s * 512;      // bias = 512x512 fp32 PE table
    }
#pragma unroll
    for (int n = 0; n < 4; ++n) {
      int col = n0 + wn + n * 16 + fr;
      float pv = (MODE == 0) ? per[col] : 0.f;
#pragma unroll
      for (int j = 0; j < 4; ++j) {
        int row = m0 + wm + mm * 16 + fq * 4 + j;
        float v = acc[mm][n][j];
        if (MODE == 1) v = fmaxf(v + bv[n], 0.f);
        if (MODE == 0) v += pv;
        __hip_bfloat16 hb = __float2bfloat16(v);
        myC[(size_t)row * ldC + col] = *(short*)&hb;
      }
    }
  }
}

// ============ prep: converts + wfc fold + PE table, ONE launch ============
__device__ __forceinline__ void cvt8(const float* in, short* out, int i) {
  const float4* p = (const float4*)(in + (size_t)i * 8);
  float4 a = p[0], b = p[1];
  union { __hip_bfloat16 h[8]; short8 s; } u;
  u.h[0] = __float2bfloat16(a.x); u.h[1] = __float2bfloat16(a.y);
  u.h[2] = __float2bfloat16(a.z); u.h[3] = __float2bfloat16(a.w);
  u.h[4] = __float2bfloat16(b.x); u.h[5] = __float2bfloat16(b.y);
  u.h[6] = __float2bfloat16(b.z); u.h[7] = __float2bfloat16(b.w);
  *(short8*)(out + (size_t)i * 8) = u.s;
}

__global__ __launch_bounds__(256) void prep(
    const float* __restrict__ x, const float* __restrict__ W1,
    const float* __restrict__ W2, const float* __restrict__ Wq,
    const float* __restrict__ Wfc,
    short* __restrict__ xb, short* __restrict__ W1b,
    short* __restrict__ W2b, short* __restrict__ Wqb,
    float* __restrict__ wsum, float* __restrict__ pe) {
  int b = blockIdx.x, t = threadIdx.x;
  if (b < 2048) {
    cvt8(x, xb, b * 256 + t);
  } else if (b < 2560) {
    cvt8(W1, W1b, (b - 2048) * 256 + t);
  } else if (b < 3072) {
    cvt8(W2, W2b, (b - 2560) * 256 + t);
  } else if (b < 3200) {
    cvt8(Wq, Wqb, (b - 3072) * 256 + t);
  } else if (b < 3328) {
    int idx = (b - 3200) * 256 + t;  // 32768
    int n = idx >> 6, d = idx & 63;
    float s = 0.f;
#pragma unroll
    for (int j = 0; j < 8; ++j) s += Wfc[(size_t)n * 512 + j * 64 + d];
    wsum[idx] = s;
  } else {
    // PE table: pe[s][c], one trig per thread (parallel, not serial chains)
    int idx = (b - 3328) * 256 + t;  // 262144
    int s = idx >> 9, c = idx & 511;
    float f = expf(-(float)(c >> 1) * LN10K_OVER_256);
    float ang = (float)s * f;
    pe[idx] = (c & 1) ? cosf(ang) : sinf(ang);
  }
}

// ============ attn_g: per-group attention + fused LN1 (128 blocks) ============
__global__ __launch_bounds__(256) void attn_g(
    const short* __restrict__ qb, const float* __restrict__ x,
    const float* __restrict__ wsum, const float* __restrict__ g1,
    const float* __restrict__ be1, float* __restrict__ o1,
    short* __restrict__ o1b) {
  int g = blockIdx.x;
  int hw = g >> 3, i = g & 7;
  int t = threadIdx.x;
  __shared__ short sl[512 * 72];       // [512 rows][64 cols + 8 pad] bf16
  __shared__ float a_[512];
  __shared__ float adist_[512];
  __shared__ float pctx[4][64];
  __shared__ float gb[1024];
  __shared__ float redA[4], redB[4], redMS[2];
  __shared__ float ctxs[64];

  gb[t] = g1[t]; gb[t + 256] = g1[t + 256];
  gb[512 + t] = be1[t]; gb[768 + t] = be1[t + 256];

  {
    const short* qsrc = qb + ((size_t)hw * 512) * 512 + i * 64;
    int chunk = t & 7, jr0 = t >> 3;
#pragma unroll
    for (int rep = 0; rep < 16; ++rep) {
      int j = jr0 + rep * 32;
      *(short8*)&sl[j * 72 + chunk * 8] =
          *(const short8*)(qsrc + (size_t)j * 512 + chunk * 8);
    }
  }
  __syncthreads();

  float r0 = 0.f, r1 = 0.f;
#pragma unroll
  for (int c = 0; c < 8; ++c) {
    union { short8 s8; short e[8]; } u0, u1;
    u0.s8 = *(const short8*)&sl[t * 72 + c * 8];
    u1.s8 = *(const short8*)&sl[(t + 256) * 72 + c * 8];
#pragma unroll
    for (int u = 0; u < 8; ++u) {
      r0 += __bfloat162float(*(__hip_bfloat16*)&u0.e[u]);
      r1 += __bfloat162float(*(__hip_bfloat16*)&u1.e[u]);
    }
  }
  float m = fmaxf(r0, r1);
  for (int off = 32; off; off >>= 1) m = fmaxf(m, __shfl_down(m, off));
  int wid = t >> 6, lane = t & 63;
  if (lane == 0) redA[wid] = m;
  __syncthreads();
  if (t == 0) redMS[0] = fmaxf(fmaxf(redA[0], redA[1]), fmaxf(redA[2], redA[3]));
  __syncthreads();
  float M = redMS[0];
  float e0 = expf(r0 - M), e1 = expf(r1 - M);
  float s = e0 + e1;
  for (int off = 32; off; off >>= 1) s += __shfl_down(s, off);
  if (lane == 0) redB[wid] = s;
  __syncthreads();
  if (t == 0) redMS[1] = redB[0] + redB[1] + redB[2] + redB[3];
  __syncthreads();
  float inv = 1.f / redMS[1];
  a_[t] = e0 * inv;
  a_[t + 256] = e1 * inv;
  __syncthreads();

  {
    int d = t & 63, seg = t >> 6;
    float acc = 0.f;
    for (int mm = seg * 128; mm < seg * 128 + 128; ++mm)
      acc += a_[mm] * __bfloat162float(*(__hip_bfloat16*)&sl[mm * 72 + d]);
    pctx[seg][d] = acc;
  }
  __syncthreads();
  if (t < 64) ctxs[t] = pctx[0][t] + pctx[1][t] + pctx[2][t] + pctx[3][t];
  __syncthreads();

  for (int n = t; n < 512; n += 256) {
    const float4* wr = (const float4*)(wsum + (size_t)n * 64);
    float sa = 0.f;
#pragma unroll
    for (int db = 0; db < 16; ++db) {
      float4 wv = wr[db];
      float4 cv = *(const float4*)&ctxs[db * 4];
      sa += cv.x * wv.x + cv.y * wv.y + cv.z * wv.z + cv.w * wv.w;
    }
    adist_[n] = sa;
  }
  __syncthreads();

  const float4* x4 = (const float4*)x;
  int w = t >> 6;
#pragma unroll 1
  for (int u = 0; u < 16; ++u) {
    int j = i * 64 + w * 16 + u;
    size_t R = (size_t)hw * 512 + j;
    float4 xv0 = x4[R * 128 + lane * 2];
    float4 xv1 = x4[R * 128 + lane * 2 + 1];
    float4 a0 = *(const float4*)&adist_[lane * 8];
    float4 a1 = *(const float4*)&adist_[lane * 8 + 4];
    float v[8] = {xv0.x + a0.x, xv0.y + a0.y, xv0.z + a0.z, xv0.w + a0.w,
                  xv1.x + a1.x, xv1.y + a1.y, xv1.z + a1.z, xv1.w + a1.w};
    float sm_ = 0.f, sq = 0.f;
#pragma unroll
    for (int q = 0; q < 8; ++q) { sm_ += v[q]; sq += v[q] * v[q]; }
    for (int off = 32; off; off >>= 1) {
      sm_ += __shfl_xor(sm_, off);
      sq += __shfl_xor(sq, off);
    }
    float mean = sm_ * (1.f / 512.f);
    float var = sq * (1.f / 512.f) - mean * mean;
    float rinv = rsqrtf(var + 1e-5f);
    float o[8];
    union { __hip_bfloat16 h[8]; short8 s8; } ub;
#pragma unroll
    for (int q = 0; q < 8; ++q) {
      int c = lane * 8 + q;
      o[q] = (v[q] - mean) * rinv * gb[c] + gb[512 + c];
      ub.h[q] = __float2bfloat16(o[q]);
    }
    float4 w0 = {o[0], o[1], o[2], o[3]};
    float4 w1 = {o[4], o[5], o[6], o[7]};
    *(float4*)&o1[R * 512 + lane * 8] = w0;
    *(float4*)&o1[R * 512 + lane * 8 + 4] = w1;
    *(short8*)&o1b[R * 512 + lane * 8] = ub.s8;
  }
}

// ============ final LN fused with split-K reduce ============
__global__ __launch_bounds__(256) void ln2_fused(
    const float* __restrict__ o1,
    const short* __restrict__ p0, const short* __restrict__ p1,
    const short* __restrict__ p2, const short* __restrict__ p3,
    const float* __restrict__ b2, const float* __restrict__ gamma,
    const float* __restrict__ beta, float* __restrict__ Out) {
  int r = blockIdx.x;
  int t = threadIdx.x;
  size_t base = (size_t)r * 512;
  float v[2];
#pragma unroll
  for (int h = 0; h < 2; ++h) {
    int c = t + h * 256;
    float f = b2[c];
    f += __bfloat162float(*(const __hip_bfloat16*)&p0[base + c]);
    f += __bfloat162float(*(const __hip_bfloat16*)&p1[base + c]);
    f += __bfloat162float(*(const __hip_bfloat16*)&p2[base + c]);
    f += __bfloat162float(*(const __hip_bfloat16*)&p3[base + c]);
    v[h] = o1[base + c] + f;
  }
  float s = v[0] + v[1], sq = v[0] * v[0] + v[1] * v[1];
  __shared__ float red[6];
  __shared__ float redA[4];
  __shared__ float redB[4];
  for (int off = 32; off; off >>= 1) {
    s += __shfl_down(s, off);
    sq += __shfl_down(sq, off);
  }
  int wid = t >> 6, lane = t & 63;
  if (lane == 0) { redA[wid] = s; redB[wid] = sq; }
  __syncthreads();
  if (t == 0) {
    float S = redA[0] + redA[1] + redA[2] + redA[3];
    float Q = redB[0] + redB[1] + redB[2] + redB[3];
    float mean = S * (1.f / 512.f);
    float var = Q * (1.f / 512.f) - mean * mean;
    red[4] = mean;
    red[5] = rsqrtf(var + 1e-5f);
  }
  __syncthreads();
  float mean = red[4], inv = red[5];
  Out[base + t] = (v[0] - mean) * inv * gamma[t] + beta[t];
  Out[base + t + 256] = (v[1] - mean) * inv * gamma[t + 256] + beta[t + 256];
}

extern "C" void kernel_launch(void* const* d_in, const int* in_sizes, int n_in,
                              void* d_out, int out_size, void* d_ws, size_t ws_size,
                              hipStream_t stream) {
  const float* x   = (const float*)d_in[0];
  const float* Wq  = (const float*)d_in[1];
  const float* Wfc = (const float*)d_in[2];
  const float* W1  = (const float*)d_in[3];
  const float* b1  = (const float*)d_in[4];
  const float* W2  = (const float*)d_in[5];
  const float* b2  = (const float*)d_in[6];
  const float* g1  = (const float*)d_in[7];
  const float* be1 = (const float*)d_in[8];
  const float* g2  = (const float*)d_in[9];
  const float* be2 = (const float*)d_in[10];
  float* out = (float*)d_out;

  char* ws = (char*)d_ws;
  float* o1   = (float*)(ws);                  // 16 MB
  short* h1b  = (short*)(ws + (16u << 20));    // 32 MB
  short* pz0  = (short*)(ws + (48u << 20));    // 8 MB
  short* pz1  = (short*)(ws + (56u << 20));    // 8 MB
  short* o1b  = (short*)(ws + (64u << 20));    // 8 MB (dead after FFN1)
  short* pz2  = (short*)(ws + (64u << 20));    //   overlays o1b
  short* pz3  = (short*)(ws + (72u << 20));    // 8 MB
  short* W1b  = (short*)(ws + (80u << 20));    // 2 MB
  short* W2b  = (short*)(ws + (82u << 20));    // 2 MB
  short* Wqb  = (short*)(ws + (84u << 20));    // 0.5 MB
  short* xb   = (short*)(ws + (85u << 20));    // 8 MB
  short* qb   = (short*)(ws + (93u << 20));    // 8 MB
  float* wsum = (float*)(ws + (101u << 20));   // 128 KB
  float* pe   = (float*)(ws + (101u << 20) + (128u << 10));  // 1 MB (end ~102.2 MB)

  // 1. converts + wfc fold + PE table
  prep<<<4352, 256, 0, stream>>>(x, W1, W2, Wq, Wfc, xb, W1b, W2b, Wqb, wsum, pe);
  // 2. qb = xb @ Wqb^T + pe (bf16); pe table passed via `bias`
  gemm256<0, 16><<<dim3(2, 32, 1), 512, 0, stream>>>(
      xb, Wqb, pe, qb, qb, qb, qb, 512, 512, 512);
  // 3. per-group attention + fused LN1
  attn_g<<<128, 256, 0, stream>>>(qb, x, wsum, g1, be1, o1, o1b);
  // 4. h1b = relu(o1b @ W1b^T + b1)
  gemm256<1, 16><<<dim3(8, 32, 1), 512, 0, stream>>>(
      o1b, W1b, b1, h1b, h1b, h1b, h1b, 2048, 512, 512);
  // 5. FFN2 split-K=4 partials (bf16)
  gemm256<3, 16><<<dim3(2, 32, 4), 512, 0, stream>>>(
      h1b, W2b, nullptr, pz0, pz1, pz2, pz3, 512, 2048, 2048);
  // 6. out = LN(o1 + sum partials + b2)
  ln2_fused<<<8192, 256, 0, stream>>>(o1, pz0, pz1, pz2, pz3, b2, g2, be2, out);
}

// Round 7
// 103.084 us; speedup vs baseline: 1.7067x; 1.1219x over previous
//
#include <hip/hip_runtime.h>
#include <hip/hip_bf16.h>
#include <math.h>

// Dims fixed: S=512, H=4, W=4, D=512, dff=2048, NH=8, depth=64. M = 8192 rows.
//
// Pipeline (6 launches):
//  1. prep: xb,W1b,W2b,Wqb bf16 converts + wsum fold + PE table (512x512 fp32)
//  2. qb = xb @ Wqb^T + pe          (gemm128 MODE 0, 256 blocks, full K)
//  3. attn_g (128 blocks): group attention + fused LN1 -> o1 (f32) + o1b (bf16)
//  4. h1b = relu(o1b @ W1b^T + b1)  (gemm256 MODE 1, 256 blocks)
//  5. f2b = h1b @ W2b^T + b2        (gemm128 MODE 2, 256 blocks, K=2048, NO split-K)
//  6. out = LN(o1 + f2b)            (ln2_fused)

typedef short short8 __attribute__((ext_vector_type(8)));
typedef float f32x4 __attribute__((ext_vector_type(4)));

#define LN10K_OVER_256 0.03597789207803197f

__device__ __forceinline__ void gload16(const short* g, short* l) {
  __builtin_amdgcn_global_load_lds(
      (const __attribute__((address_space(1))) void*)g,
      (__attribute__((address_space(3))) void*)l, 16, 0, 0);
}

#define BAR() do { asm volatile("" ::: "memory"); \
                   __builtin_amdgcn_s_barrier();  \
                   asm volatile("" ::: "memory"); } while (0)

// paired-row swizzled LDS: conceptual [rows][32 cols] bf16, super-row = 2 rows
// (8 slots of 16B), slot ^= (super_row & 7). Staging writes linear t*8 shorts;
// the read-side XOR and the pre-swizzled global source are the same involution.
__device__ __forceinline__ short8 ldsfrag(const short* opbuf, int R, int fq) {
  int sr = R >> 1;
  int sp = (((R & 1) << 2) | fq) ^ (sr & 7);
  return *(const short8*)(opbuf + sr * 64 + sp * 8);
}

// ============ 256x256/BK32, 8-wave, 3-deep pipelined bf16 GEMM ============
template<bool DOSTAGE, int WAITK>
__device__ __forceinline__ void tile_step(
    short* ldsb, int cur, int nx, int tt, int koff,
    const short* Ag0, const short* Ag1, const short* Bg0, const short* Bg1,
    int w, int fr, int fq, int wm, int wn, f32x4 (&acc)[8][4]) {
  const short* Abuf = ldsb + cur * 16384;
  const short* Bbuf = Abuf + 8192;
  short8 af[4], bfr[4];
#pragma unroll
  for (int m = 0; m < 4; ++m) af[m] = ldsfrag(Abuf, wm + m * 16 + fr, fq);
#pragma unroll
  for (int n = 0; n < 4; ++n) bfr[n] = ldsfrag(Bbuf, wn + n * 16 + fr, fq);
  if (DOSTAGE) {
    int kb = koff + (tt + 2) * 32;
    gload16(Ag0 + kb, ldsb + nx * 16384 + w * 512);
    gload16(Ag1 + kb, ldsb + nx * 16384 + 4096 + w * 512);
  }
  BAR();
  __builtin_amdgcn_s_setprio(1);
#pragma unroll
  for (int m = 0; m < 4; ++m)
#pragma unroll
    for (int n = 0; n < 4; ++n)
      acc[m][n] = __builtin_amdgcn_mfma_f32_16x16x32_bf16(af[m], bfr[n],
                                                          acc[m][n], 0, 0, 0);
  __builtin_amdgcn_s_setprio(0);
  BAR();
#pragma unroll
  for (int m = 0; m < 4; ++m) af[m] = ldsfrag(Abuf, wm + 64 + m * 16 + fr, fq);
  if (DOSTAGE) {
    int kb = koff + (tt + 2) * 32;
    gload16(Bg0 + kb, ldsb + nx * 16384 + 8192 + w * 512);
    gload16(Bg1 + kb, ldsb + nx * 16384 + 8192 + 4096 + w * 512);
  }
  BAR();
  __builtin_amdgcn_s_setprio(1);
#pragma unroll
  for (int m = 0; m < 4; ++m)
#pragma unroll
    for (int n = 0; n < 4; ++n)
      acc[4 + m][n] = __builtin_amdgcn_mfma_f32_16x16x32_bf16(af[m], bfr[n],
                                                              acc[4 + m][n], 0, 0, 0);
  __builtin_amdgcn_s_setprio(0);
  if (WAITK == 4) asm volatile("s_waitcnt vmcnt(4)" ::: "memory");
  else if (WAITK == 0) asm volatile("s_waitcnt vmcnt(0)" ::: "memory");
  BAR();
}

// MODE 1 only: relu(acc + bias[col]) -> bf16 C0.  (FFN1)
template<int MODE, int NT>
__global__ __launch_bounds__(512) void gemm256(
    const short* __restrict__ A, const short* __restrict__ B,
    const float* __restrict__ bias, short* __restrict__ C0,
    int ldC, int ldA, int ldB) {
  __shared__ short lds[3 * 2 * 8192];  // 96 KiB
  const int t = threadIdx.x;
  const int w = t >> 6, l = t & 63;
  const int fr = l & 15, fq = l >> 4;
  const int wm = (w >> 2) * 128;
  const int wn = (w & 3) * 64;
  const int m0 = blockIdx.y * 256, n0 = blockIdx.x * 256;
  const int koff = 0;

  const int scont = (t & 7) ^ ((t >> 3) & 7);
  const int Rbase = ((t >> 3) << 1) | (scont >> 2);
  const int cg = (scont & 3) << 3;
  const short* Ag0 = A + (size_t)(m0 + Rbase) * ldA + cg;
  const short* Ag1 = Ag0 + (size_t)128 * ldA;
  const short* Bg0 = B + (size_t)(n0 + Rbase) * ldB + cg;
  const short* Bg1 = Bg0 + (size_t)128 * ldB;
  short* ldsb = &lds[0];

  gload16(Ag0, ldsb + w * 512);
  gload16(Ag1, ldsb + 4096 + w * 512);
  gload16(Bg0, ldsb + 8192 + w * 512);
  gload16(Bg1, ldsb + 8192 + 4096 + w * 512);
  gload16(Ag0 + 32, ldsb + 16384 + w * 512);
  gload16(Ag1 + 32, ldsb + 16384 + 4096 + w * 512);
  gload16(Bg0 + 32, ldsb + 16384 + 8192 + w * 512);
  gload16(Bg1 + 32, ldsb + 16384 + 8192 + 4096 + w * 512);
  asm volatile("s_waitcnt vmcnt(4)" ::: "memory");
  BAR();

  f32x4 acc[8][4] = {};
  int cur = 0;
#pragma unroll 1
  for (int tt = 0; tt < NT - 2; ++tt) {
    int nx = cur + 2; if (nx >= 3) nx -= 3;
    tile_step<true, 4>(ldsb, cur, nx, tt, koff, Ag0, Ag1, Bg0, Bg1,
                       w, fr, fq, wm, wn, acc);
    if (++cur == 3) cur = 0;
  }
  tile_step<false, 0>(ldsb, cur, 0, NT - 2, koff, Ag0, Ag1, Bg0, Bg1,
                      w, fr, fq, wm, wn, acc);
  { int c2 = cur + 1; if (c2 >= 3) c2 -= 3;
    tile_step<false, -1>(ldsb, c2, 0, NT - 1, koff, Ag0, Ag1, Bg0, Bg1,
                         w, fr, fq, wm, wn, acc); }

  float bv[4];
#pragma unroll
  for (int n = 0; n < 4; ++n) bv[n] = bias[n0 + wn + n * 16 + fr];
#pragma unroll
  for (int mm = 0; mm < 8; ++mm) {
#pragma unroll
    for (int n = 0; n < 4; ++n) {
      int col = n0 + wn + n * 16 + fr;
#pragma unroll
      for (int j = 0; j < 4; ++j) {
        int row = m0 + wm + mm * 16 + fq * 4 + j;
        float v = fmaxf(acc[mm][n][j] + bv[n], 0.f);
        __hip_bfloat16 hb = __float2bfloat16(v);
        C0[(size_t)row * ldC + col] = *(short*)&hb;
      }
    }
  }
}

// ============ 128x128/BK32, 4-wave, 3-deep pipelined bf16 GEMM ============
// Same swizzle / barrier / vmcnt(4) discipline as gemm256, halved geometry.
// MODE 0: acc + pe[(row>>4)][col] (bias = 512x512 PE table). MODE 2: acc + bias[col].
template<bool DOSTAGE, int WAITK>
__device__ __forceinline__ void tile_step128(
    short* ldsb, int cur, int nx, int tt,
    const short* Ag0, const short* Ag1, const short* Bg0, const short* Bg1,
    int w, int fr, int fq, int wm, int wn, f32x4 (&acc)[4][4]) {
  const short* Abuf = ldsb + cur * 8192;
  const short* Bbuf = Abuf + 4096;
  short8 af[4], bfr[4];
#pragma unroll
  for (int m = 0; m < 4; ++m) af[m] = ldsfrag(Abuf, wm + m * 16 + fr, fq);
#pragma unroll
  for (int n = 0; n < 4; ++n) bfr[n] = ldsfrag(Bbuf, wn + n * 16 + fr, fq);
  if (DOSTAGE) {
    int kb = (tt + 2) * 32;
    gload16(Ag0 + kb, ldsb + nx * 8192 + w * 512);
    gload16(Ag1 + kb, ldsb + nx * 8192 + 2048 + w * 512);
    gload16(Bg0 + kb, ldsb + nx * 8192 + 4096 + w * 512);
    gload16(Bg1 + kb, ldsb + nx * 8192 + 6144 + w * 512);
  }
  BAR();
  __builtin_amdgcn_s_setprio(1);
#pragma unroll
  for (int m = 0; m < 4; ++m)
#pragma unroll
    for (int n = 0; n < 4; ++n)
      acc[m][n] = __builtin_amdgcn_mfma_f32_16x16x32_bf16(af[m], bfr[n],
                                                          acc[m][n], 0, 0, 0);
  __builtin_amdgcn_s_setprio(0);
  if (WAITK == 4) asm volatile("s_waitcnt vmcnt(4)" ::: "memory");
  else if (WAITK == 0) asm volatile("s_waitcnt vmcnt(0)" ::: "memory");
  BAR();
}

template<int MODE, int NT>
__global__ __launch_bounds__(256) void gemm128(
    const short* __restrict__ A, const short* __restrict__ B,
    const float* __restrict__ bias, short* __restrict__ C,
    int ldC, int ldA, int ldB) {
  __shared__ short lds[3 * 8192];  // 48 KiB: 3 bufs x (A 4K + B 4K shorts)
  const int t = threadIdx.x;
  const int w = t >> 6, l = t & 63;
  const int fr = l & 15, fq = l >> 4;
  const int wm = (w >> 1) * 64;
  const int wn = (w & 1) * 64;
  const int m0 = blockIdx.y * 128, n0 = blockIdx.x * 128;

  const int scont = (t & 7) ^ ((t >> 3) & 7);
  const int Rbase = ((t >> 3) << 1) | (scont >> 2);  // [0,64)
  const int cg = (scont & 3) << 3;
  const short* Ag0 = A + (size_t)(m0 + Rbase) * ldA + cg;
  const short* Ag1 = Ag0 + (size_t)64 * ldA;
  const short* Bg0 = B + (size_t)(n0 + Rbase) * ldB + cg;
  const short* Bg1 = Bg0 + (size_t)64 * ldB;
  short* ldsb = &lds[0];

  // prologue: tile0 -> buf0, tile1 -> buf1; wait tile0 (4 in flight)
  gload16(Ag0, ldsb + w * 512);
  gload16(Ag1, ldsb + 2048 + w * 512);
  gload16(Bg0, ldsb + 4096 + w * 512);
  gload16(Bg1, ldsb + 6144 + w * 512);
  gload16(Ag0 + 32, ldsb + 8192 + w * 512);
  gload16(Ag1 + 32, ldsb + 8192 + 2048 + w * 512);
  gload16(Bg0 + 32, ldsb + 8192 + 4096 + w * 512);
  gload16(Bg1 + 32, ldsb + 8192 + 6144 + w * 512);
  asm volatile("s_waitcnt vmcnt(4)" ::: "memory");
  BAR();

  f32x4 acc[4][4] = {};
  int cur = 0;
#pragma unroll 1
  for (int tt = 0; tt < NT - 2; ++tt) {
    int nx = cur + 2; if (nx >= 3) nx -= 3;
    tile_step128<true, 4>(ldsb, cur, nx, tt, Ag0, Ag1, Bg0, Bg1,
                          w, fr, fq, wm, wn, acc);
    if (++cur == 3) cur = 0;
  }
  tile_step128<false, 0>(ldsb, cur, 0, NT - 2, Ag0, Ag1, Bg0, Bg1,
                         w, fr, fq, wm, wn, acc);
  { int c2 = cur + 1; if (c2 >= 3) c2 -= 3;
    tile_step128<false, -1>(ldsb, c2, 0, NT - 1, Ag0, Ag1, Bg0, Bg1,
                            w, fr, fq, wm, wn, acc); }

  float bv[4];
  if (MODE == 2) {
#pragma unroll
    for (int n = 0; n < 4; ++n) bv[n] = bias[n0 + wn + n * 16 + fr];
  }
#pragma unroll
  for (int mm = 0; mm < 4; ++mm) {
    const float* per = nullptr;
    if (MODE == 0) {
      int s = (m0 + wm + mm * 16) >> 4;  // uniform over fq*4+j within this mm
      per = bias + (size_t)s * 512;      // bias = 512x512 fp32 PE table
    }
#pragma unroll
    for (int n = 0; n < 4; ++n) {
      int col = n0 + wn + n * 16 + fr;
      float pv = (MODE == 0) ? per[col] : bv[n];
#pragma unroll
      for (int j = 0; j < 4; ++j) {
        int row = m0 + wm + mm * 16 + fq * 4 + j;
        float v = acc[mm][n][j] + pv;
        __hip_bfloat16 hb = __float2bfloat16(v);
        C[(size_t)row * ldC + col] = *(short*)&hb;
      }
    }
  }
}

// ============ prep: converts + wfc fold + PE table, ONE launch ============
__device__ __forceinline__ void cvt8(const float* in, short* out, int i) {
  const float4* p = (const float4*)(in + (size_t)i * 8);
  float4 a = p[0], b = p[1];
  union { __hip_bfloat16 h[8]; short8 s; } u;
  u.h[0] = __float2bfloat16(a.x); u.h[1] = __float2bfloat16(a.y);
  u.h[2] = __float2bfloat16(a.z); u.h[3] = __float2bfloat16(a.w);
  u.h[4] = __float2bfloat16(b.x); u.h[5] = __float2bfloat16(b.y);
  u.h[6] = __float2bfloat16(b.z); u.h[7] = __float2bfloat16(b.w);
  *(short8*)(out + (size_t)i * 8) = u.s;
}

__global__ __launch_bounds__(256) void prep(
    const float* __restrict__ x, const float* __restrict__ W1,
    const float* __restrict__ W2, const float* __restrict__ Wq,
    const float* __restrict__ Wfc,
    short* __restrict__ xb, short* __restrict__ W1b,
    short* __restrict__ W2b, short* __restrict__ Wqb,
    float* __restrict__ wsum, float* __restrict__ pe) {
  int b = blockIdx.x, t = threadIdx.x;
  if (b < 2048) {
    cvt8(x, xb, b * 256 + t);
  } else if (b < 2560) {
    cvt8(W1, W1b, (b - 2048) * 256 + t);
  } else if (b < 3072) {
    cvt8(W2, W2b, (b - 2560) * 256 + t);
  } else if (b < 3200) {
    cvt8(Wq, Wqb, (b - 3072) * 256 + t);
  } else if (b < 3328) {
    int idx = (b - 3200) * 256 + t;  // 32768
    int n = idx >> 6, d = idx & 63;
    float s = 0.f;
#pragma unroll
    for (int j = 0; j < 8; ++j) s += Wfc[(size_t)n * 512 + j * 64 + d];
    wsum[idx] = s;
  } else {
    int idx = (b - 3328) * 256 + t;  // 262144
    int s = idx >> 9, c = idx & 511;
    float f = expf(-(float)(c >> 1) * LN10K_OVER_256);
    float ang = (float)s * f;
    pe[idx] = (c & 1) ? cosf(ang) : sinf(ang);
  }
}

// ============ attn_g: per-group attention + fused LN1 (128 blocks) ============
__global__ __launch_bounds__(256) void attn_g(
    const short* __restrict__ qb, const float* __restrict__ x,
    const float* __restrict__ wsum, const float* __restrict__ g1,
    const float* __restrict__ be1, float* __restrict__ o1,
    short* __restrict__ o1b) {
  int g = blockIdx.x;
  int hw = g >> 3, i = g & 7;
  int t = threadIdx.x;
  __shared__ short sl[512 * 72];       // [512 rows][64 cols + 8 pad] bf16
  __shared__ float a_[512];
  __shared__ float adist_[512];
  __shared__ float pctx[4][64];
  __shared__ float gb[1024];
  __shared__ float redA[4], redB[4], redMS[2];
  __shared__ float ctxs[64];

  gb[t] = g1[t]; gb[t + 256] = g1[t + 256];
  gb[512 + t] = be1[t]; gb[768 + t] = be1[t + 256];

  {
    const short* qsrc = qb + ((size_t)hw * 512) * 512 + i * 64;
    int chunk = t & 7, jr0 = t >> 3;
#pragma unroll
    for (int rep = 0; rep < 16; ++rep) {
      int j = jr0 + rep * 32;
      *(short8*)&sl[j * 72 + chunk * 8] =
          *(const short8*)(qsrc + (size_t)j * 512 + chunk * 8);
    }
  }
  __syncthreads();

  float r0 = 0.f, r1 = 0.f;
#pragma unroll
  for (int c = 0; c < 8; ++c) {
    union { short8 s8; short e[8]; } u0, u1;
    u0.s8 = *(const short8*)&sl[t * 72 + c * 8];
    u1.s8 = *(const short8*)&sl[(t + 256) * 72 + c * 8];
#pragma unroll
    for (int u = 0; u < 8; ++u) {
      r0 += __bfloat162float(*(__hip_bfloat16*)&u0.e[u]);
      r1 += __bfloat162float(*(__hip_bfloat16*)&u1.e[u]);
    }
  }
  float m = fmaxf(r0, r1);
  for (int off = 32; off; off >>= 1) m = fmaxf(m, __shfl_down(m, off));
  int wid = t >> 6, lane = t & 63;
  if (lane == 0) redA[wid] = m;
  __syncthreads();
  if (t == 0) redMS[0] = fmaxf(fmaxf(redA[0], redA[1]), fmaxf(redA[2], redA[3]));
  __syncthreads();
  float M = redMS[0];
  float e0 = expf(r0 - M), e1 = expf(r1 - M);
  float s = e0 + e1;
  for (int off = 32; off; off >>= 1) s += __shfl_down(s, off);
  if (lane == 0) redB[wid] = s;
  __syncthreads();
  if (t == 0) redMS[1] = redB[0] + redB[1] + redB[2] + redB[3];
  __syncthreads();
  float inv = 1.f / redMS[1];
  a_[t] = e0 * inv;
  a_[t + 256] = e1 * inv;
  __syncthreads();

  {
    int d = t & 63, seg = t >> 6;
    float acc = 0.f;
    for (int mm = seg * 128; mm < seg * 128 + 128; ++mm)
      acc += a_[mm] * __bfloat162float(*(__hip_bfloat16*)&sl[mm * 72 + d]);
    pctx[seg][d] = acc;
  }
  __syncthreads();
  if (t < 64) ctxs[t] = pctx[0][t] + pctx[1][t] + pctx[2][t] + pctx[3][t];
  __syncthreads();

  for (int n = t; n < 512; n += 256) {
    const float4* wr = (const float4*)(wsum + (size_t)n * 64);
    float sa = 0.f;
#pragma unroll
    for (int db = 0; db < 16; ++db) {
      float4 wv = wr[db];
      float4 cv = *(const float4*)&ctxs[db * 4];
      sa += cv.x * wv.x + cv.y * wv.y + cv.z * wv.z + cv.w * wv.w;
    }
    adist_[n] = sa;
  }
  __syncthreads();

  const float4* x4 = (const float4*)x;
  int w = t >> 6;
#pragma unroll 1
  for (int u = 0; u < 16; ++u) {
    int j = i * 64 + w * 16 + u;
    size_t R = (size_t)hw * 512 + j;
    float4 xv0 = x4[R * 128 + lane * 2];
    float4 xv1 = x4[R * 128 + lane * 2 + 1];
    float4 a0 = *(const float4*)&adist_[lane * 8];
    float4 a1 = *(const float4*)&adist_[lane * 8 + 4];
    float v[8] = {xv0.x + a0.x, xv0.y + a0.y, xv0.z + a0.z, xv0.w + a0.w,
                  xv1.x + a1.x, xv1.y + a1.y, xv1.z + a1.z, xv1.w + a1.w};
    float sm_ = 0.f, sq = 0.f;
#pragma unroll
    for (int q = 0; q < 8; ++q) { sm_ += v[q]; sq += v[q] * v[q]; }
    for (int off = 32; off; off >>= 1) {
      sm_ += __shfl_xor(sm_, off);
      sq += __shfl_xor(sq, off);
    }
    float mean = sm_ * (1.f / 512.f);
    float var = sq * (1.f / 512.f) - mean * mean;
    float rinv = rsqrtf(var + 1e-5f);
    float o[8];
    union { __hip_bfloat16 h[8]; short8 s8; } ub;
#pragma unroll
    for (int q = 0; q < 8; ++q) {
      int c = lane * 8 + q;
      o[q] = (v[q] - mean) * rinv * gb[c] + gb[512 + c];
      ub.h[q] = __float2bfloat16(o[q]);
    }
    float4 w0 = {o[0], o[1], o[2], o[3]};
    float4 w1 = {o[4], o[5], o[6], o[7]};
    *(float4*)&o1[R * 512 + lane * 8] = w0;
    *(float4*)&o1[R * 512 + lane * 8 + 4] = w1;
    *(short8*)&o1b[R * 512 + lane * 8] = ub.s8;
  }
}

// ============ final LN: out = LN(o1 + f2b), b2 already folded into f2b ============
__global__ __launch_bounds__(256) void ln2_fused(
    const float* __restrict__ o1, const short* __restrict__ f2,
    const float* __restrict__ gamma, const float* __restrict__ beta,
    float* __restrict__ Out) {
  int r = blockIdx.x;
  int t = threadIdx.x;
  size_t base = (size_t)r * 512;
  float v0 = o1[base + t] +
             __bfloat162float(*(const __hip_bfloat16*)&f2[base + t]);
  float v1 = o1[base + t + 256] +
             __bfloat162float(*(const __hip_bfloat16*)&f2[base + t + 256]);
  float s = v0 + v1, sq = v0 * v0 + v1 * v1;
  __shared__ float red[6];
  __shared__ float redA[4];
  __shared__ float redB[4];
  for (int off = 32; off; off >>= 1) {
    s += __shfl_down(s, off);
    sq += __shfl_down(sq, off);
  }
  int wid = t >> 6, lane = t & 63;
  if (lane == 0) { redA[wid] = s; redB[wid] = sq; }
  __syncthreads();
  if (t == 0) {
    float S = redA[0] + redA[1] + redA[2] + redA[3];
    float Q = redB[0] + redB[1] + redB[2] + redB[3];
    float mean = S * (1.f / 512.f);
    float var = Q * (1.f / 512.f) - mean * mean;
    red[4] = mean;
    red[5] = rsqrtf(var + 1e-5f);
  }
  __syncthreads();
  float mean = red[4], inv = red[5];
  Out[base + t] = (v0 - mean) * inv * gamma[t] + beta[t];
  Out[base + t + 256] = (v1 - mean) * inv * gamma[t + 256] + beta[t + 256];
}

extern "C" void kernel_launch(void* const* d_in, const int* in_sizes, int n_in,
                              void* d_out, int out_size, void* d_ws, size_t ws_size,
                              hipStream_t stream) {
  const float* x   = (const float*)d_in[0];
  const float* Wq  = (const float*)d_in[1];
  const float* Wfc = (const float*)d_in[2];
  const float* W1  = (const float*)d_in[3];
  const float* b1  = (const float*)d_in[4];
  const float* W2  = (const float*)d_in[5];
  const float* b2  = (const float*)d_in[6];
  const float* g1  = (const float*)d_in[7];
  const float* be1 = (const float*)d_in[8];
  const float* g2  = (const float*)d_in[9];
  const float* be2 = (const float*)d_in[10];
  float* out = (float*)d_out;

  char* ws = (char*)d_ws;
  float* o1   = (float*)(ws);                  // 16 MB
  short* h1b  = (short*)(ws + (16u << 20));    // 32 MB
  short* f2b  = (short*)(ws + (48u << 20));    // 8 MB
  short* o1b  = (short*)(ws + (56u << 20));    // 8 MB
  short* W1b  = (short*)(ws + (64u << 20));    // 2 MB
  short* W2b  = (short*)(ws + (66u << 20));    // 2 MB
  short* Wqb  = (short*)(ws + (68u << 20));    // 0.5 MB
  short* xb   = (short*)(ws + (69u << 20));    // 8 MB
  short* qb   = (short*)(ws + (77u << 20));    // 8 MB
  float* wsum = (float*)(ws + (85u << 20));    // 128 KB
  float* pe   = (float*)(ws + (85u << 20) + (128u << 10));  // 1 MB (end ~86.2 MB)

  // 1. converts + wfc fold + PE table
  prep<<<4352, 256, 0, stream>>>(x, W1, W2, Wq, Wfc, xb, W1b, W2b, Wqb, wsum, pe);
  // 2. qb = xb @ Wqb^T + pe (bf16); 256 blocks, full K=512
  gemm128<0, 16><<<dim3(4, 64), 256, 0, stream>>>(
      xb, Wqb, pe, qb, 512, 512, 512);
  // 3. per-group attention + fused LN1
  attn_g<<<128, 256, 0, stream>>>(qb, x, wsum, g1, be1, o1, o1b);
  // 4. h1b = relu(o1b @ W1b^T + b1); 256 blocks
  gemm256<1, 16><<<dim3(8, 32), 512, 0, stream>>>(
      o1b, W1b, b1, h1b, 2048, 512, 512);
  // 5. f2b = h1b @ W2b^T + b2; 256 blocks, full K=2048, no split-K
  gemm128<2, 64><<<dim3(4, 64), 256, 0, stream>>>(
      h1b, W2b, b2, f2b, 512, 2048, 2048);
  // 6. out = LN(o1 + f2b)
  ln2_fused<<<8192, 256, 0, stream>>>(o1, f2b, g2, be2, out);
}